// Round 6
// baseline (134.610 us; speedup 1.0000x reference)
//
#include <hip/hip_runtime.h>

#define SCALE_F 512.0f

// ws layout (float offsets)
#define WS_H     0        // B*S*E = 131072 floats
#define WS_GPART 131072   // 1024 blocks * 8 experts = 8192 floats

static __device__ __forceinline__ float4 f4add(float4 a, float4 b) {
    return make_float4(a.x + b.x, a.y + b.y, a.z + b.z, a.w + b.w);
}

// __builtin_nontemporal_* requires a clang vector type, not HIP_vector_type.
typedef __attribute__((ext_vector_type(4))) float cf4;

static __device__ __forceinline__ float4 nt_load4(const float4* p) {
    cf4 v = __builtin_nontemporal_load((const cf4*)p);
    return make_float4(v.x, v.y, v.z, v.w);
}

// ---------------- Kernel A: h[tok,e] for all 8 experts + per-block gate partials
// grid 1024 x 256; 16 tokens/block in two 8-token sub-tiles (32KB LDS reused).
// wave w owns weight rows 4w..4w+3: rows 0..7 = lora_A, rows 8..15 = gate_w.
// Gate waves (w>=2) accumulate across all 16 tokens, butterfly ONCE at the end.
// NOTE: no cooperative groups anywhere — grid-sync fusion twice compiled to a
// 64-VGPR spill (rounds 2/5: 213-219us, VALUBusy 4%). Plain kernels allocate
// enough VGPRs to hold W[4][4] (round-1 evidence: kA never showed in top-5).
__global__ __launch_bounds__(256) void kA_h_gate(
    const float* __restrict__ x, const float* __restrict__ lora_A,
    const float* __restrict__ gate_w, float* __restrict__ h,
    float* __restrict__ gpart)
{
    const int tid      = threadIdx.x;
    const int w        = tid >> 6;
    const int lane     = tid & 63;
    const int tok_base = blockIdx.x * 16;

    __shared__ __align__(16) float xbuf[8 * 1024];   // 32 KB

    // Wave's 4 weight rows in registers: 16 floats/lane/row at float4 idx lane+64j.
    float4 W[4][4];
#pragma unroll
    for (int rr = 0; rr < 4; ++rr) {
        const int row = 4 * w + rr;
        const float* rp = (row < 8) ? (lora_A + row * 1024)
                                    : (gate_w + (row - 8) * 1024);
        const float4* rp4 = (const float4*)rp;
#pragma unroll
        for (int j = 0; j < 4; ++j) W[rr][j] = rp4[lane + 64 * j];
    }

    float gacc[4] = {0.f, 0.f, 0.f, 0.f};

#pragma unroll
    for (int ti = 0; ti < 2; ++ti) {
        const int tok0 = tok_base + ti * 8;

        if (ti) __syncthreads();   // all waves done reading xbuf before restage

        // stage 8 token rows (read-once stream -> nontemporal, keep L2 clean)
        const float4* src = (const float4*)(x + (size_t)tok0 * 1024);
        float4* dst = (float4*)xbuf;
#pragma unroll
        for (int j = 0; j < 8; ++j)
            dst[tid + 256 * j] = nt_load4(&src[tid + 256 * j]);
        __syncthreads();

#pragma unroll 2
        for (int t = 0; t < 8; ++t) {
            const float4* xr = (const float4*)(xbuf + t * 1024);
            const float4 xv0 = xr[lane];
            const float4 xv1 = xr[lane + 64];
            const float4 xv2 = xr[lane + 128];
            const float4 xv3 = xr[lane + 192];

            float p[4];
#pragma unroll
            for (int rr = 0; rr < 4; ++rr) {
                const float4 a0 = W[rr][0], a1 = W[rr][1];
                const float4 a2 = W[rr][2], a3 = W[rr][3];
                float s;
                s  = xv0.x * a0.x + xv0.y * a0.y + xv0.z * a0.z + xv0.w * a0.w;
                s += xv1.x * a1.x + xv1.y * a1.y + xv1.z * a1.z + xv1.w * a1.w;
                s += xv2.x * a2.x + xv2.y * a2.y + xv2.z * a2.z + xv2.w * a2.w;
                s += xv3.x * a3.x + xv3.y * a3.y + xv3.z * a3.z + xv3.w * a3.w;
                p[rr] = s;
            }

            if (w < 2) {
                // per-token full reduction needed for h rows
#pragma unroll
                for (int off = 32; off > 0; off >>= 1) {
                    p[0] += __shfl_xor(p[0], off);
                    p[1] += __shfl_xor(p[1], off);
                    p[2] += __shfl_xor(p[2], off);
                    p[3] += __shfl_xor(p[3], off);
                }
                if (lane == 0) {
                    float4 hv = make_float4(p[0], p[1], p[2], p[3]);
                    *(float4*)(h + (size_t)(tok0 + t) * 8 + w * 4) = hv;
                }
            } else {
                // gate rows: only the token-sum matters
                gacc[0] += p[0]; gacc[1] += p[1]; gacc[2] += p[2]; gacc[3] += p[3];
            }
        }
    }

    if (w >= 2) {
        // single butterfly for the 16-token-summed gate partials
#pragma unroll
        for (int off = 32; off > 0; off >>= 1) {
            gacc[0] += __shfl_xor(gacc[0], off);
            gacc[1] += __shfl_xor(gacc[1], off);
            gacc[2] += __shfl_xor(gacc[2], off);
            gacc[3] += __shfl_xor(gacc[3], off);
        }
        if (lane == 0) {
            float4 gv = make_float4(gacc[0], gacc[1], gacc[2], gacc[3]);
            *(float4*)(gpart + (size_t)blockIdx.x * 8 + (w - 2) * 4) = gv;
        }
    }
}

// ---------------- Kernel B: gate finalize (redundant per-block, L2-resident)
// + combine. grid 1024 x 256; 16 tokens/block (same mapping as kA).
// Per-batch gpart slice is now 256 blocks * 8 floats = 8 KB.
__global__ __launch_bounds__(256) void kB_gate_combine(
    const float* __restrict__ h, const float* __restrict__ gpart,
    const float* __restrict__ gate_b, const float* __restrict__ lora_B,
    float* __restrict__ out)
{
    const int tid  = threadIdx.x;
    const int blk  = blockIdx.x;
    const int b    = blk >> 8;            // 256 blocks per batch
    const int tok0 = blk * 16;

    __shared__ float4 s4[256];
    __shared__ float  s_h[128];
    __shared__ float  s_logit[8];
    __shared__ int    s_sel[2];
    __shared__ float  s_coef[2];

    // batch-b gate slice: 512 float4 (8 KB), L2-resident.
    // float4-index parity == expert group (even = e0..3, odd = e4..7);
    // parity is preserved through every tree stride below.
    const float4* gp4 = (const float4*)(gpart + (size_t)b * 2048);
    s4[tid] = f4add(gp4[tid], gp4[tid + 256]);

    // stage this block's h rows: 128 consecutive floats, coalesced
    if (tid < 128) s_h[tid] = h[(size_t)tok0 * 8 + tid];
    __syncthreads();

    if (tid < 64) {
        s4[tid] = f4add(f4add(s4[tid], s4[tid + 64]),
                        f4add(s4[tid + 128], s4[tid + 192]));
    }
    __syncthreads();
    if (tid < 16) {
        s4[tid] = f4add(f4add(s4[tid], s4[tid + 16]),
                        f4add(s4[tid + 32], s4[tid + 48]));
    }
    __syncthreads();
    if (tid < 2) {
        float4 a = s4[tid];
#pragma unroll
        for (int q = 2; q < 16; q += 2) a = f4add(a, s4[tid + q]);
        const float inv = 1.0f / 4096.0f;
        s_logit[tid * 4 + 0] = a.x * inv + gate_b[tid * 4 + 0];
        s_logit[tid * 4 + 1] = a.y * inv + gate_b[tid * 4 + 1];
        s_logit[tid * 4 + 2] = a.z * inv + gate_b[tid * 4 + 2];
        s_logit[tid * 4 + 3] = a.w * inv + gate_b[tid * 4 + 3];
    }
    __syncthreads();

    if (tid == 0) {
        float sc[8];
        float m = -1e30f;
#pragma unroll
        for (int q = 0; q < 8; ++q) { sc[q] = s_logit[q]; m = fmaxf(m, sc[q]); }
        float sum = 0.f;
#pragma unroll
        for (int q = 0; q < 8; ++q) { sc[q] = __expf(sc[q] - m); sum += sc[q]; }
        const float invs = 1.0f / sum;

        int i0 = 0;
#pragma unroll
        for (int q = 1; q < 8; ++q) if (sc[q] > sc[i0]) i0 = q;
        int i1 = (i0 == 0) ? 1 : 0;
#pragma unroll
        for (int q = 0; q < 8; ++q) if (q != i0 && sc[q] > sc[i1]) i1 = q;

        s_sel[0]  = i0;
        s_sel[1]  = i1;
        s_coef[0] = SCALE_F * sc[i0] * invs;
        s_coef[1] = SCALE_F * sc[i1] * invs;
    }
    __syncthreads();

    const int   i0 = s_sel[0];
    const int   i1 = s_sel[1];
    const float c0 = s_coef[0];
    const float c1 = s_coef[1];

    const float4 b0 = ((const float4*)(lora_B + i0 * 1024))[tid];
    const float4 b1 = ((const float4*)(lora_B + i1 * 1024))[tid];
    const float4 v0 = make_float4(c0 * b0.x, c0 * b0.y, c0 * b0.z, c0 * b0.w);
    const float4 v1 = make_float4(c1 * b1.x, c1 * b1.y, c1 * b1.z, c1 * b1.w);

    // plain (cached, write-back) stores for out: round-5's nt-store fallback
    // measured 134.4 vs round-1's 128.7 — nt-store is the suspect.
    float4* out4 = (float4*)out;
#pragma unroll
    for (int t = 0; t < 16; ++t) {
        const float h0 = s_h[t * 8 + i0];
        const float h1 = s_h[t * 8 + i1];
        float4 r;
        r.x = h0 * v0.x + h1 * v1.x;
        r.y = h0 * v0.y + h1 * v1.y;
        r.z = h0 * v0.z + h1 * v1.z;
        r.w = h0 * v0.w + h1 * v1.w;
        out4[(size_t)(tok0 + t) * 256 + tid] = r;
    }
}

extern "C" void kernel_launch(void* const* d_in, const int* in_sizes, int n_in,
                              void* d_out, int out_size, void* d_ws, size_t ws_size,
                              hipStream_t stream) {
    const float* x      = (const float*)d_in[0];
    const float* lora_A = (const float*)d_in[1];
    const float* lora_B = (const float*)d_in[2];
    const float* gate_w = (const float*)d_in[3];
    const float* gate_b = (const float*)d_in[4];
    float* out = (float*)d_out;

    float* ws    = (float*)d_ws;
    float* h     = ws + WS_H;
    float* gpart = ws + WS_GPART;

    kA_h_gate<<<1024, 256, 0, stream>>>(x, lora_A, gate_w, h, gpart);
    kB_gate_combine<<<1024, 256, 0, stream>>>(h, gpart, gate_b, lora_B, out);
}

// Round 7
// 129.991 us; speedup vs baseline: 1.0355x; 1.0355x over previous
//
#include <hip/hip_runtime.h>

#define SCALE_F 512.0f

// ws layout (float offsets)
#define WS_H     0        // B*S*E = 131072 floats
#define WS_GPART 131072   // 2048 blocks * 8 experts = 16384 floats

static __device__ __forceinline__ float4 f4add(float4 a, float4 b) {
    return make_float4(a.x + b.x, a.y + b.y, a.z + b.z, a.w + b.w);
}

// ---------------- Kernel A: h[b,s,e] for all 8 experts + per-block gate partials
// grid 2048 x 256; 8 tokens/block (32KB LDS); wave w owns weight rows 4w..4w+3
// rows 0..7 = lora_A experts, rows 8..15 = gate_w experts. NO atomics.
// Round-1-proven structure (128.7us). No nontemporal hints (134us rounds 5/6
// both carried nt-load; round 1 without it was fastest). No cooperative groups
// (grid-sync fusion compiles to a 64-VGPR spill: rounds 2/5, 213-219us).
__global__ __launch_bounds__(256) void kA_h_gate(
    const float* __restrict__ x, const float* __restrict__ lora_A,
    const float* __restrict__ gate_w, float* __restrict__ h,
    float* __restrict__ gpart)
{
    const int tid  = threadIdx.x;
    const int w    = tid >> 6;
    const int lane = tid & 63;
    const int tok0 = blockIdx.x * 8;       // global token base

    __shared__ __align__(16) float xbuf[8 * 1024];   // 8 token rows, 32 KB

    // Issue the x staging loads FIRST — they are the HBM long pole; W rows are
    // L2-resident after the first blocks. 24 loads in flight before any wait.
    const float4* src = (const float4*)(x + (size_t)tok0 * 1024);
    float4 xs[8];
#pragma unroll
    for (int j = 0; j < 8; ++j) xs[j] = src[tid + 256 * j];

    // Wave's 4 weight rows in registers: 16 floats/lane/row at float4 idx lane+64j.
    float4 W[4][4];
#pragma unroll
    for (int rr = 0; rr < 4; ++rr) {
        const int row = 4 * w + rr;
        const float* rp = (row < 8) ? (lora_A + row * 1024)
                                    : (gate_w + (row - 8) * 1024);
        const float4* rp4 = (const float4*)rp;
#pragma unroll
        for (int j = 0; j < 4; ++j) W[rr][j] = rp4[lane + 64 * j];
    }

    // drain staged x into LDS (xs dies here; regs reused for compute)
    float4* dst = (float4*)xbuf;
#pragma unroll
    for (int j = 0; j < 8; ++j) dst[tid + 256 * j] = xs[j];
    __syncthreads();

    float gacc[4] = {0.f, 0.f, 0.f, 0.f};

#pragma unroll 2
    for (int t = 0; t < 8; ++t) {
        const float4* xr = (const float4*)(xbuf + t * 1024);
        const float4 xv0 = xr[lane];
        const float4 xv1 = xr[lane + 64];
        const float4 xv2 = xr[lane + 128];
        const float4 xv3 = xr[lane + 192];

        float p[4];
#pragma unroll
        for (int rr = 0; rr < 4; ++rr) {
            const float4 a0 = W[rr][0], a1 = W[rr][1];
            const float4 a2 = W[rr][2], a3 = W[rr][3];
            float s;
            s  = xv0.x * a0.x + xv0.y * a0.y + xv0.z * a0.z + xv0.w * a0.w;
            s += xv1.x * a1.x + xv1.y * a1.y + xv1.z * a1.z + xv1.w * a1.w;
            s += xv2.x * a2.x + xv2.y * a2.y + xv2.z * a2.z + xv2.w * a2.w;
            s += xv3.x * a3.x + xv3.y * a3.y + xv3.z * a3.z + xv3.w * a3.w;
            p[rr] = s;
        }

        if (w < 2) {
            // per-token full reduction needed for h rows
#pragma unroll
            for (int off = 32; off > 0; off >>= 1) {
                p[0] += __shfl_xor(p[0], off);
                p[1] += __shfl_xor(p[1], off);
                p[2] += __shfl_xor(p[2], off);
                p[3] += __shfl_xor(p[3], off);
            }
            if (lane == 0) {
                float4 hv = make_float4(p[0], p[1], p[2], p[3]);
                *(float4*)(h + (size_t)(tok0 + t) * 8 + w * 4) = hv;
            }
        } else {
            // gate rows: only the token-sum matters -> accumulate raw partials
            gacc[0] += p[0]; gacc[1] += p[1]; gacc[2] += p[2]; gacc[3] += p[3];
        }
    }

    if (w >= 2) {
        // single butterfly for the token-summed gate partials
#pragma unroll
        for (int off = 32; off > 0; off >>= 1) {
            gacc[0] += __shfl_xor(gacc[0], off);
            gacc[1] += __shfl_xor(gacc[1], off);
            gacc[2] += __shfl_xor(gacc[2], off);
            gacc[3] += __shfl_xor(gacc[3], off);
        }
        if (lane == 0) {
            float4 gv = make_float4(gacc[0], gacc[1], gacc[2], gacc[3]);
            *(float4*)(gpart + (size_t)blockIdx.x * 8 + (w - 2) * 4) = gv;
        }
    }
}

// ---------------- Kernel B: gate finalize + combine, ONE barrier.
// grid 2048 x 256; 8 tokens/block.
// Wave 0: reduces the batch's 16KB gpart slice (L2-resident) with a
// parity-preserving butterfly + in-register softmax/top2 -> s_sel/s_coef.
// Wave 1: stages this block's 64 h floats. Single __syncthreads, then all
// 256 threads combine. (Replaces round-1's 4-barrier LDS reduce tree.)
__global__ __launch_bounds__(256) void kB_gate_combine(
    const float* __restrict__ h, const float* __restrict__ gpart,
    const float* __restrict__ gate_b, const float* __restrict__ lora_B,
    float* __restrict__ out)
{
    const int tid  = threadIdx.x;
    const int w    = tid >> 6;
    const int lane = tid & 63;
    const int blk  = blockIdx.x;
    const int b    = blk >> 9;            // 512 blocks per batch
    const int tok0 = blk * 8;

    __shared__ float s_h[64];
    __shared__ int   s_sel[2];
    __shared__ float s_coef[2];

    if (w == 1) {
        // stage this block's h rows: 64 consecutive floats, one coalesced read
        s_h[lane] = h[(size_t)tok0 * 8 + lane];
    } else if (w == 0) {
        // batch-b gate slice: 1024 float4 (16 KB), L2-resident.
        // float4-index parity == expert group (even = e0..3, odd = e4..7);
        // lane parity == float4 parity for idx = lane + 64k.
        const float4* gp4 = (const float4*)(gpart + (size_t)b * 4096);
        float4 acc = make_float4(0.f, 0.f, 0.f, 0.f);
#pragma unroll
        for (int k = 0; k < 16; ++k) acc = f4add(acc, gp4[lane + 64 * k]);

        // butterfly over offsets 32..2 only: keeps even/odd lane classes
        // separate, so every even lane ends with the e0..3 totals and every
        // odd lane with the e4..7 totals.
#pragma unroll
        for (int off = 32; off >= 2; off >>= 1) {
            acc.x += __shfl_xor(acc.x, off);
            acc.y += __shfl_xor(acc.y, off);
            acc.z += __shfl_xor(acc.z, off);
            acc.w += __shfl_xor(acc.w, off);
        }
        // cross the parity split: lane 0 fetches lane 1's class totals
        const float o0 = __shfl_xor(acc.x, 1);
        const float o1 = __shfl_xor(acc.y, 1);
        const float o2 = __shfl_xor(acc.z, 1);
        const float o3 = __shfl_xor(acc.w, 1);

        if (lane == 0) {
            const float inv = 1.0f / 4096.0f;
            float sc[8];
            sc[0] = acc.x * inv + gate_b[0];
            sc[1] = acc.y * inv + gate_b[1];
            sc[2] = acc.z * inv + gate_b[2];
            sc[3] = acc.w * inv + gate_b[3];
            sc[4] = o0 * inv + gate_b[4];
            sc[5] = o1 * inv + gate_b[5];
            sc[6] = o2 * inv + gate_b[6];
            sc[7] = o3 * inv + gate_b[7];

            float m = -1e30f;
#pragma unroll
            for (int q = 0; q < 8; ++q) m = fmaxf(m, sc[q]);
            float sum = 0.f;
#pragma unroll
            for (int q = 0; q < 8; ++q) { sc[q] = __expf(sc[q] - m); sum += sc[q]; }
            const float invs = 1.0f / sum;

            int i0 = 0;
#pragma unroll
            for (int q = 1; q < 8; ++q) if (sc[q] > sc[i0]) i0 = q;
            int i1 = (i0 == 0) ? 1 : 0;
#pragma unroll
            for (int q = 0; q < 8; ++q) if (q != i0 && sc[q] > sc[i1]) i1 = q;

            s_sel[0]  = i0;
            s_sel[1]  = i1;
            s_coef[0] = SCALE_F * sc[i0] * invs;
            s_coef[1] = SCALE_F * sc[i1] * invs;
        }
    }
    __syncthreads();

    const int   i0 = s_sel[0];
    const int   i1 = s_sel[1];
    const float c0 = s_coef[0];
    const float c1 = s_coef[1];

    const float4 b0 = ((const float4*)(lora_B + i0 * 1024))[tid];
    const float4 b1 = ((const float4*)(lora_B + i1 * 1024))[tid];
    const float4 v0 = make_float4(c0 * b0.x, c0 * b0.y, c0 * b0.z, c0 * b0.w);
    const float4 v1 = make_float4(c1 * b1.x, c1 * b1.y, c1 * b1.z, c1 * b1.w);

    float4* out4 = (float4*)out;
#pragma unroll
    for (int t = 0; t < 8; ++t) {
        const float h0 = s_h[t * 8 + i0];
        const float h1 = s_h[t * 8 + i1];
        float4 r;
        r.x = h0 * v0.x + h1 * v1.x;
        r.y = h0 * v0.y + h1 * v1.y;
        r.z = h0 * v0.z + h1 * v1.z;
        r.w = h0 * v0.w + h1 * v1.w;
        out4[(size_t)(tok0 + t) * 256 + tid] = r;
    }
}

extern "C" void kernel_launch(void* const* d_in, const int* in_sizes, int n_in,
                              void* d_out, int out_size, void* d_ws, size_t ws_size,
                              hipStream_t stream) {
    const float* x      = (const float*)d_in[0];
    const float* lora_A = (const float*)d_in[1];
    const float* lora_B = (const float*)d_in[2];
    const float* gate_w = (const float*)d_in[3];
    const float* gate_b = (const float*)d_in[4];
    float* out = (float*)d_out;

    float* ws    = (float*)d_ws;
    float* h     = ws + WS_H;
    float* gpart = ws + WS_GPART;

    kA_h_gate<<<2048, 256, 0, stream>>>(x, lora_A, gate_w, h, gpart);
    kB_gate_combine<<<2048, 256, 0, stream>>>(h, gpart, gate_b, lora_B, out);
}